// Round 7
// baseline (232.505 us; speedup 1.0000x reference)
//
#include <hip/hip_runtime.h>
#include <math.h>

// Problem geometry (fixed by setup_inputs)
#define NN 2
#define DD 160
#define HH 192
#define WW 160
#define DO 154   // DD-6
#define HO 186   // HH-6
#define WO 154   // WW-6

#define NWO 3    // wo tiles of 64
#define HOT 8    // ho tile
#define NHO 24   // ceil(186/8)
#define ZCH 7    // z chunks: 154 = 7*22 exactly -> every block nslice=28=2*14
#define ZOC 22
#define NSL 28   // ZOC+6, compile-time constant for ALL blocks
#define NB (NWO * NHO * NN * ZCH)   // 1008 blocks (~3.94/CU)

// LDS-only barrier: s_waitcnt lgkmcnt(0) (vmcnt left outstanding) + s_barrier.
// Global prefetch loads stay in flight across the barrier (CK block_sync_lds).
#define LDS_SYNC() do { __builtin_amdgcn_s_waitcnt(0xC07F); __builtin_amdgcn_s_barrier(); } while (0)

__device__ __forceinline__ float block_sum(float v, float* sm) {
  int tid = threadIdx.x;
  sm[tid] = v;
  __syncthreads();
#pragma unroll
  for (int off = 128; off > 0; off >>= 1) {
    if (tid < off) sm[tid] += sm[tid + off];
    __syncthreads();
  }
  float r = sm[0];
  __syncthreads();
  return r;
}

__device__ __forceinline__ float block_min(float v, float* sm) {
  int tid = threadIdx.x;
  sm[tid] = v;
  __syncthreads();
#pragma unroll
  for (int off = 128; off > 0; off >>= 1) {
    if (tid < off) sm[tid] = fminf(sm[tid], sm[tid + off]);
    __syncthreads();
  }
  float r = sm[0];
  __syncthreads();
  return r;
}

__device__ __forceinline__ float wave_sum(float v) {
  v += __shfl_xor(v, 32); v += __shfl_xor(v, 16); v += __shfl_xor(v, 8);
  v += __shfl_xor(v, 4);  v += __shfl_xor(v, 2);  v += __shfl_xor(v, 1);
  return v;
}

__device__ __forceinline__ float wave_min(float v) {
  v = fminf(v, __shfl_xor(v, 32)); v = fminf(v, __shfl_xor(v, 16));
  v = fminf(v, __shfl_xor(v, 8));  v = fminf(v, __shfl_xor(v, 4));
  v = fminf(v, __shfl_xor(v, 2));  v = fminf(v, __shfl_xor(v, 1));
  return v;
}

__device__ __forceinline__ float2 f2add(float2 a, float2 b) {
  return make_float2(a.x + b.x, a.y + b.y);
}
__device__ __forceinline__ float2 f2slide(float2 m, float2 s, float2 n) {
  return make_float2(m.x - s.x + n.x, m.y - s.y + n.y);
}

// 7-tap sliding W-sum over 10 inputs -> 4 outputs (one float4 store).
// W4 at row stride 64: bank-quad residues {0,4,...,28} get exactly 8 lanes each
// = the 8-round minimum -> conflict-free (r3 measured 0 conflicts).
#define SLIDE7(V, M) do { \
  float s0 = ((V[0]+V[1])+(V[2]+V[3])) + ((V[4]+V[5])+V[6]); \
  float s1 = s0 - V[0] + V[7]; \
  float s2 = s1 - V[1] + V[8]; \
  float s3 = s2 - V[2] + V[9]; \
  *(float4*)&R[M][rA][c4] = make_float4(s0, s1, s2, s3); \
} while (0)

// Global->reg load into register set P (P = (s_in)&1, literal). 2-deep pipeline:
// issued at iteration s for slice s+2, consumed by STOREA in iteration s+1 ->
// ~1 full slice period in flight (> ~900cy HBM latency) -> no vmcnt stall.
#define LOADA(P, SIN) do { if (okA) { \
  const float* xp = XrowA + (size_t)(z0 + (SIN)) * slice; \
  const float* yp = YrowA + (size_t)(z0 + (SIN)) * slice; \
  lx0_##P = *(const float4*)xp;       lx1_##P = *(const float4*)(xp + 4); \
  ly0_##P = *(const float4*)yp;       ly1_##P = *(const float4*)(yp + 4); \
  if (!tail) { lx2_##P = *(const float2*)(xp + 8); ly2_##P = *(const float2*)(yp + 8); } \
  else       { lx2_##P = make_float2(0.f, 0.f);    ly2_##P = make_float2(0.f, 0.f); } \
} } while (0)

#define STOREA(P) do { if (okA) { \
  const float x[10] = {lx0_##P.x,lx0_##P.y,lx0_##P.z,lx0_##P.w, \
                       lx1_##P.x,lx1_##P.y,lx1_##P.z,lx1_##P.w, lx2_##P.x,lx2_##P.y}; \
  const float y[10] = {ly0_##P.x,ly0_##P.y,ly0_##P.z,ly0_##P.w, \
                       ly1_##P.x,ly1_##P.y,ly1_##P.z,ly1_##P.w, ly2_##P.x,ly2_##P.y}; \
  SLIDE7(x, 0); \
  SLIDE7(y, 1); \
  { float t[10]; \
    _Pragma("unroll") for (int i = 0; i < 10; ++i) t[i] = x[i] * x[i]; \
    SLIDE7(t, 2); } \
  { float t[10]; \
    _Pragma("unroll") for (int i = 0; i < 10; ++i) t[i] = y[i] * y[i]; \
    SLIDE7(t, 3); } \
  { float t[10]; \
    _Pragma("unroll") for (int i = 0; i < 10; ++i) t[i] = x[i] * y[i]; \
    SLIDE7(t, 4); } \
} } while (0)

// Phase O with static ring index U (0..6). Two rows (ty, ty+4) per thread.
#define PHASEO(U, S) do { \
  float ma0 = Mh[0][ty][tx], mb0 = Mh[0][ty+4][tx]; \
  float ma1 = Mh[1][ty][tx], mb1 = Mh[1][ty+4][tx]; \
  float ma2 = Mh[2][ty][tx], mb2 = Mh[2][ty+4][tx]; \
  float ma3 = Mh[3][ty][tx], mb3 = Mh[3][ty+4][tx]; \
  float ma4 = Mh[4][ty][tx], mb4 = Mh[4][ty+4][tx]; \
  zs0[0] += ma0 - h0[0][U]; h0[0][U] = ma0;  zs0[1] += mb0 - h0[1][U]; h0[1][U] = mb0; \
  zs1[0] += ma1 - h1[0][U]; h1[0][U] = ma1;  zs1[1] += mb1 - h1[1][U]; h1[1][U] = mb1; \
  zs2[0] += ma2 - h2[0][U]; h2[0][U] = ma2;  zs2[1] += mb2 - h2[1][U]; h2[1][U] = mb2; \
  zs3[0] += ma3 - h3[0][U]; h3[0][U] = ma3;  zs3[1] += mb3 - h3[1][U]; h3[1][U] = mb3; \
  zs4[0] += ma4 - h4[0][U]; h4[0][U] = ma4;  zs4[1] += mb4 - h4[1][U]; h4[1][U] = mb4; \
  if ((S) >= 6) { \
    if (act0) { \
      float num = zs4[0] - zs0[0] * zs1[0] * inv_nw; \
      float d0  = zs2[0] - zs0[0] * zs0[0] * inv_nw; \
      float d1  = zs3[0] - zs1[0] * zs1[0] * inv_nw; \
      float den = d0 * d1; \
      if (den > 1e-5f) { \
        float ncc = num * __frsqrt_rn(den); \
        if (ncc >= LO && ncc <= HI) { \
          float v = 0.5f * (d0 + d1); \
          p_snv += ncc * v; p_sn += ncc; p_sv += v; p_cnt += 1.f; \
          p_vmin = fminf(p_vmin, v); \
        } } } \
    if (act1) { \
      float num = zs4[1] - zs0[1] * zs1[1] * inv_nw; \
      float d0  = zs2[1] - zs0[1] * zs0[1] * inv_nw; \
      float d1  = zs3[1] - zs1[1] * zs1[1] * inv_nw; \
      float den = d0 * d1; \
      if (den > 1e-5f) { \
        float ncc = num * __frsqrt_rn(den); \
        if (ncc >= LO && ncc <= HI) { \
          float v = 0.5f * (d0 + d1); \
          p_snv += ncc * v; p_sn += ncc; p_sv += v; p_cnt += 1.f; \
          p_vmin = fminf(p_vmin, v); \
        } } } \
  } \
} while (0)

// One pipeline step. K literal 0..13; P = K&1 (load reg set for slice s+2);
// Q = 1-P (reg set consumed by storeA(s+1)); U = K%7 (z-ring slot, == s%7
// since base is a multiple of 14).
#define STEP(K, P, Q, U) do { \
  const int s = base + (K); \
  if (s + 2 < NSL) LOADA(P, s + 2); \
  phaseH(); \
  LDS_SYNC(); \
  PHASEO(U, s); \
  if (s + 1 < NSL) STOREA(Q); \
  LDS_SYNC(); \
} while (0)

// (256,3): do NOT tighten to (256,4) — that caps unified VGPR/AGPR at 128 and
// forces the Z-history ring into scratch (round-2: 31 MB HBM writeback).
__global__ __launch_bounds__(256, 3) void ncc_fused(const float* __restrict__ X,
                                                    const float* __restrict__ Y,
                                                    float* __restrict__ part) {
  __shared__ __align__(16) float R[5][14][64];   // 17.9 KB W-filtered moment rows
  __shared__ __align__(16) float Mh[5][HOT][64]; // 10.2 KB W+H-filtered moments
  __shared__ float red[4][5];

  const int tid = threadIdx.x;
  const int tx = tid & 63, ty = tid >> 6;
  const int wo0 = blockIdx.x * 64;
  const int ho0 = blockIdx.y * HOT;
  const int n   = blockIdx.z / ZCH;
  const int ck  = blockIdx.z % ZCH;
  const int z0  = ck * ZOC;

  const int wo = wo0 + tx;
  const bool act0 = (wo < WO) && (ho0 + ty < HO);
  const bool act1 = (wo < WO) && (ho0 + ty + 4 < HO);

  const size_t slice = (size_t)HH * WW;
  const float* Xn = X + (size_t)n * DD * slice;
  const float* Yn = Y + (size_t)n * DD * slice;
  const float inv_nw = 1.0f / 343.0f;
  const float LO = -1.0f - 1e-5f, HI = 1.0f + 1e-5f;

  // Phase-A item: 224 items; item p -> row rA=p>>4 (0..13), 4 outputs at cols c4..c4+3.
  const int pA  = tid;
  const bool hasA = (pA < 224);
  const int rA  = pA >> 4;
  const int c4  = (pA & 15) << 2;
  const int hA  = ho0 + rA;
  const int baseW = wo0 + c4;                  // multiple of 4
  const bool okA  = hasA && (hA < HH) && (baseW < WO);
  const bool tail = okA && (baseW + 10 > WW);  // only baseW==152: read 8, zero 2
  const float* XrowA = Xn + (size_t)hA * WW + baseW;
  const float* YrowA = Yn + (size_t)hA * WW + baseW;

  // Two register sets for the 2-deep load pipeline (static names, rule #20).
  float4 lx0_0={0,0,0,0}, lx1_0={0,0,0,0}; float2 lx2_0={0,0};
  float4 ly0_0={0,0,0,0}, ly1_0={0,0,0,0}; float2 ly2_0={0,0};
  float4 lx0_1={0,0,0,0}, lx1_1={0,0,0,0}; float2 lx2_1={0,0};
  float4 ly0_1={0,0,0,0}, ly1_1={0,0,0,0}; float2 ly2_1={0,0};

  // Phase H (b64): 160 items = (ch 0..4) x (wp 0..31).
  //   lanes tx<32 of wave w -> ch=w;  wave 3 lanes tx>=32 -> ch=4 (those lanes
  //   are A-idle, so wave 3's pre-barrier work stays balanced).
  // Reads: 14 ds_read_b64 down column-pair wp of R (row stride 32 float2);
  // writes 8 ds_write_b64 into Mh. Wave-inst count 110 b32 -> 22 b64/wave:
  // LDS floor/block-slice ~1110 -> ~870 cyc.
  const bool okH = (tx < 32) || (ty == 3);
  const int chH = (tx < 32) ? ty : 4;
  const int wpH = tx & 31;
  const float2* rpH = (const float2*)&R[chH][0][0] + wpH;   // row stride 32
  float2* mhH = (float2*)&Mh[chH][0][0] + wpH;              // row stride 32

  auto phaseH = [&]() {
    if (okH) {
      float2 r0 = rpH[0],   r1 = rpH[32],  r2 = rpH[64],  r3 = rpH[96],
             r4 = rpH[128], r5 = rpH[160], r6 = rpH[192];
      float2 m = f2add(f2add(f2add(r0, r1), f2add(r2, r3)), f2add(f2add(r4, r5), r6));
      mhH[0] = m;
      float2 nw;
      nw = rpH[224]; m = f2slide(m, r0, nw); mhH[32]  = m;
      nw = rpH[256]; m = f2slide(m, r1, nw); mhH[64]  = m;
      nw = rpH[288]; m = f2slide(m, r2, nw); mhH[96]  = m;
      nw = rpH[320]; m = f2slide(m, r3, nw); mhH[128] = m;
      nw = rpH[352]; m = f2slide(m, r4, nw); mhH[160] = m;
      nw = rpH[384]; m = f2slide(m, r5, nw); mhH[192] = m;
      nw = rpH[416]; m = f2slide(m, r6, nw); mhH[224] = m;
    }
  };

  // Sliding-window Z accumulation: zs += m_new - hist[u]; hist[u] = m_new.
  // Ring index U is a macro literal -> stays in registers/AGPRs.
  float zs0[2]={0,0}, zs1[2]={0,0}, zs2[2]={0,0}, zs3[2]={0,0}, zs4[2]={0,0};
  float h0[2][7], h1[2][7], h2[2][7], h3[2][7], h4[2][7];
#pragma unroll
  for (int j = 0; j < 7; ++j) {
    h0[0][j]=0.f; h1[0][j]=0.f; h2[0][j]=0.f; h3[0][j]=0.f; h4[0][j]=0.f;
    h0[1][j]=0.f; h1[1][j]=0.f; h2[1][j]=0.f; h3[1][j]=0.f; h4[1][j]=0.f;
  }
  float p_snv = 0.f, p_sn = 0.f, p_sv = 0.f, p_cnt = 0.f, p_vmin = 3.4e38f;

  // Prologue: slices 0 and 1 in flight; slice 0 staged to R.
  LOADA(0, 0);
  LOADA(1, 1);
  STOREA(0);
  __syncthreads();

#pragma unroll 1
  for (int base = 0; base < NSL; base += 14) {   // NSL = 28 = 2*14; base%14==0
    STEP(0, 0, 1, 0);
    STEP(1, 1, 0, 1);
    STEP(2, 0, 1, 2);
    STEP(3, 1, 0, 3);
    STEP(4, 0, 1, 4);
    STEP(5, 1, 0, 5);
    STEP(6, 0, 1, 6);
    STEP(7, 1, 0, 0);
    STEP(8, 0, 1, 1);
    STEP(9, 1, 0, 2);
    STEP(10, 0, 1, 3);
    STEP(11, 1, 0, 4);
    STEP(12, 0, 1, 5);
    STEP(13, 1, 0, 6);
  }

  // Wave-level reduction (6 shfl each), then 4 partials through LDS.
  float r0 = wave_sum(p_snv);
  float r1 = wave_sum(p_sn);
  float r2 = wave_sum(p_sv);
  float r3 = wave_sum(p_cnt);
  float r4 = wave_min(p_vmin);
  if (tx == 0) {
    red[ty][0]=r0; red[ty][1]=r1; red[ty][2]=r2; red[ty][3]=r3; red[ty][4]=r4;
  }
  __syncthreads();
  if (tid == 0) {
    float s0 = (red[0][0]+red[1][0]) + (red[2][0]+red[3][0]);
    float s1 = (red[0][1]+red[1][1]) + (red[2][1]+red[3][1]);
    float s2 = (red[0][2]+red[1][2]) + (red[2][2]+red[3][2]);
    float s3 = (red[0][3]+red[1][3]) + (red[2][3]+red[3][3]);
    float s4 = fminf(fminf(red[0][4],red[1][4]), fminf(red[2][4],red[3][4]));
    const int bid = blockIdx.x + NWO * (blockIdx.y + NHO * blockIdx.z);
    float* pp = part + (size_t)bid * 8;
    pp[0] = s0; pp[1] = s1; pp[2] = s2; pp[3] = s3; pp[4] = s4;
  }
}

// Reduce NB per-block partials; loss = 1 - (S_nv - vmin*S_n)/(S_v - vmin*cnt)
// (the min-max weight scale HIGH/(vmax-vmin+1e-12) cancels in w/sum(w)).
__global__ __launch_bounds__(256) void fin(const float* __restrict__ part,
                                           float* __restrict__ out) {
  __shared__ float sm[256];
  const int tid = threadIdx.x;
  float s0 = 0.f, s1 = 0.f, s2 = 0.f, s3 = 0.f, vm = 3.4e38f;
  for (int b = tid; b < NB; b += 256) {
    const float* pp = part + (size_t)b * 8;
    s0 += pp[0]; s1 += pp[1]; s2 += pp[2]; s3 += pp[3];
    vm = fminf(vm, pp[4]);
  }
  s0 = block_sum(s0, sm);
  s1 = block_sum(s1, sm);
  s2 = block_sum(s2, sm);
  s3 = block_sum(s3, sm);
  vm = block_min(vm, sm);
  if (tid == 0) {
    out[0] = 1.0f - (s0 - vm * s1) / (s2 - vm * s3);
  }
}

extern "C" void kernel_launch(void* const* d_in, const int* in_sizes, int n_in,
                              void* d_out, int out_size, void* d_ws, size_t ws_size,
                              hipStream_t stream) {
  const float* X = (const float*)d_in[0];  // y_pred
  const float* Y = (const float*)d_in[1];  // y_true
  // d_in[2]: ones kernel, constant, unused.

  float* part = (float*)d_ws;  // NB * 8 floats = 31.5 KB

  dim3 g(NWO, NHO, NN * ZCH);
  ncc_fused<<<g, 256, 0, stream>>>(X, Y, part);
  fin<<<1, 256, 0, stream>>>(part, (float*)d_out);
}

// Round 8
// 157.853 us; speedup vs baseline: 1.4729x; 1.4729x over previous
//
#include <hip/hip_runtime.h>
#include <math.h>

// Problem geometry (fixed by setup_inputs)
#define NN 2
#define DD 160
#define HH 192
#define WW 160
#define DO 154   // DD-6
#define HO 186   // HH-6
#define WO 154   // WW-6

#define NWO 3    // wo tiles of 64
#define HOT 8    // ho tile
#define NHO 24   // ceil(186/8)
#define ZCH 7    // z chunks: 154 = 7*22 exactly -> every block nslice=28=4*7
#define ZOC 22
#define NSL 28   // ZOC+6, compile-time constant for ALL blocks
#define NB (NWO * NHO * NN * ZCH)   // 1008 blocks

// LDS-only barrier: s_waitcnt lgkmcnt(0) (vmcnt left outstanding) + s_barrier.
#define LDS_SYNC() do { __builtin_amdgcn_s_waitcnt(0xC07F); __builtin_amdgcn_s_barrier(); } while (0)

__device__ __forceinline__ float block_sum(float v, float* sm) {
  int tid = threadIdx.x;
  sm[tid] = v;
  __syncthreads();
#pragma unroll
  for (int off = 128; off > 0; off >>= 1) {
    if (tid < off) sm[tid] += sm[tid + off];
    __syncthreads();
  }
  float r = sm[0];
  __syncthreads();
  return r;
}

__device__ __forceinline__ float block_min(float v, float* sm) {
  int tid = threadIdx.x;
  sm[tid] = v;
  __syncthreads();
#pragma unroll
  for (int off = 128; off > 0; off >>= 1) {
    if (tid < off) sm[tid] = fminf(sm[tid], sm[tid + off]);
    __syncthreads();
  }
  float r = sm[0];
  __syncthreads();
  return r;
}

__device__ __forceinline__ float wave_sum(float v) {
  v += __shfl_xor(v, 32); v += __shfl_xor(v, 16); v += __shfl_xor(v, 8);
  v += __shfl_xor(v, 4);  v += __shfl_xor(v, 2);  v += __shfl_xor(v, 1);
  return v;
}

__device__ __forceinline__ float wave_min(float v) {
  v = fminf(v, __shfl_xor(v, 32)); v = fminf(v, __shfl_xor(v, 16));
  v = fminf(v, __shfl_xor(v, 8));  v = fminf(v, __shfl_xor(v, 4));
  v = fminf(v, __shfl_xor(v, 2));  v = fminf(v, __shfl_xor(v, 1));
  return v;
}

__device__ __forceinline__ float2 f2add(float2 a, float2 b) {
  return make_float2(a.x + b.x, a.y + b.y);
}
__device__ __forceinline__ float2 f2slide(float2 m, float2 s, float2 n) {
  return make_float2(m.x - s.x + n.x, m.y - s.y + n.y);
}

// 7-tap sliding W-sum over 10 inputs -> 4 outputs (one float4 store).
// W4 at row stride 64: bank-quad residues get exactly 8 lanes each = the
// 8-round minimum -> conflict-free (r3 measured 0 conflicts).
#define SLIDE7(V, M) do { \
  float s0 = ((V[0]+V[1])+(V[2]+V[3])) + ((V[4]+V[5])+V[6]); \
  float s1 = s0 - V[0] + V[7]; \
  float s2 = s1 - V[1] + V[8]; \
  float s3 = s2 - V[2] + V[9]; \
  *(float4*)&R[M][rA][c4] = make_float4(s0, s1, s2, s3); \
} while (0)

// (256,3): do NOT tighten to (256,4) — 128-reg cap spills the Z-history ring
// (round-2: 31 MB writeback). Measured budget at (256,3): ~170 unified regs;
// r3 steady state ~150 -> NO new architectural state (round-7: +24 regs for a
// 2nd load set -> 69 MB scratch spill).
__global__ __launch_bounds__(256, 3) void ncc_fused(const float* __restrict__ X,
                                                    const float* __restrict__ Y,
                                                    float* __restrict__ part) {
  __shared__ __align__(16) float R[5][14][64];   // 17.9 KB W-filtered moment rows
  __shared__ __align__(16) float Mh[5][HOT][64]; // 10.2 KB W+H-filtered moments
  __shared__ float red[4][5];

  const int tid = threadIdx.x;
  const int tx = tid & 63, ty = tid >> 6;
  const int wo0 = blockIdx.x * 64;
  const int ho0 = blockIdx.y * HOT;
  const int n   = blockIdx.z / ZCH;
  const int ck  = blockIdx.z % ZCH;
  const int z0  = ck * ZOC;

  const int wo = wo0 + tx;
  const bool act0 = (wo < WO) && (ho0 + ty < HO);
  const bool act1 = (wo < WO) && (ho0 + ty + 4 < HO);

  const size_t slice = (size_t)HH * WW;
  const float* Xn = X + (size_t)n * DD * slice;
  const float* Yn = Y + (size_t)n * DD * slice;
  const float inv_nw = 1.0f / 343.0f;
  const float LO = -1.0f - 1e-5f, HI = 1.0f + 1e-5f;

  // Phase-A item: 224 items; item p -> row rA=p>>4 (0..13), 4 outputs at cols c4..c4+3.
  const int pA  = tid;
  const bool hasA = (pA < 224);
  const int rA  = pA >> 4;
  const int c4  = (pA & 15) << 2;
  const int hA  = ho0 + rA;
  const int baseW = wo0 + c4;                  // multiple of 4
  const bool okA  = hasA && (hA < HH) && (baseW < WO);
  const bool tail = okA && (baseW + 10 > WW);  // only baseW==152: read 8, zero 2
  const float* XrowA = Xn + (size_t)hA * WW + baseW;
  const float* YrowA = Yn + (size_t)hA * WW + baseW;

  float4 lx0={0,0,0,0}, lx1={0,0,0,0};
  float4 ly0={0,0,0,0}, ly1={0,0,0,0};
  float2 lx2={0,0}, ly2={0,0};

  auto loadA = [&](int s_in) {
    if (okA) {
      const float* xp = XrowA + (size_t)(z0 + s_in) * slice;
      const float* yp = YrowA + (size_t)(z0 + s_in) * slice;
      lx0 = *(const float4*)xp;       lx1 = *(const float4*)(xp + 4);
      ly0 = *(const float4*)yp;       ly1 = *(const float4*)(yp + 4);
      if (!tail) { lx2 = *(const float2*)(xp + 8); ly2 = *(const float2*)(yp + 8); }
      else       { lx2 = make_float2(0.f, 0.f);    ly2 = make_float2(0.f, 0.f); }
    }
  };

  auto storeA = [&]() {
    if (okA) {
      const float x[10] = {lx0.x,lx0.y,lx0.z,lx0.w, lx1.x,lx1.y,lx1.z,lx1.w, lx2.x,lx2.y};
      const float y[10] = {ly0.x,ly0.y,ly0.z,ly0.w, ly1.x,ly1.y,ly1.z,ly1.w, ly2.x,ly2.y};
      SLIDE7(x, 0);
      SLIDE7(y, 1);
      {
        float t[10];
#pragma unroll
        for (int i = 0; i < 10; ++i) t[i] = x[i] * x[i];
        SLIDE7(t, 2);
      }
      {
        float t[10];
#pragma unroll
        for (int i = 0; i < 10; ++i) t[i] = y[i] * y[i];
        SLIDE7(t, 3);
      }
      {
        float t[10];
#pragma unroll
        for (int i = 0; i < 10; ++i) t[i] = x[i] * y[i];
        SLIDE7(t, 4);
      }
    }
  };

  // Phase H (b64, wave-balanced): 160 float2-items on 40 lanes x 4 waves.
  //   i = ty*40 + tx (tx<40); ch = i>>5 (0..4), wp = i&31 (column pair).
  // Each item: 14 ds_read_b64 down column-pair wp of R (row stride 32 float2),
  // 7-tap slide, 8 ds_write_b64 into Mh. Every wave issues the same 22 DS
  // insts (r3's wave 3 did 2x the items = the barrier critical path).
  // Register-neutral vs r3: 7 live float2 = 14 regs = old 14 live scalars.
  const int iH  = ty * 40 + tx;
  const bool okH = (tx < 40);
  const int chH = iH >> 5;
  const int wpH = iH & 31;
  const float2* rpH = (const float2*)&R[0][0][0] + chH * 448 + wpH;  // ch blk 448 f2
  float2* mhH = (float2*)&Mh[0][0][0] + chH * 256 + wpH;             // ch blk 256 f2

  auto phaseH = [&]() {
    if (okH) {
      float2 r0 = rpH[0],   r1 = rpH[32],  r2 = rpH[64],  r3 = rpH[96],
             r4 = rpH[128], r5 = rpH[160], r6 = rpH[192];
      float2 m = f2add(f2add(f2add(r0, r1), f2add(r2, r3)), f2add(f2add(r4, r5), r6));
      mhH[0] = m;
      float2 nw;
      nw = rpH[224]; m = f2slide(m, r0, nw); mhH[32]  = m;
      nw = rpH[256]; m = f2slide(m, r1, nw); mhH[64]  = m;
      nw = rpH[288]; m = f2slide(m, r2, nw); mhH[96]  = m;
      nw = rpH[320]; m = f2slide(m, r3, nw); mhH[128] = m;
      nw = rpH[352]; m = f2slide(m, r4, nw); mhH[160] = m;
      nw = rpH[384]; m = f2slide(m, r5, nw); mhH[192] = m;
      nw = rpH[416]; m = f2slide(m, r6, nw); mhH[224] = m;
    }
  };

  // Sliding-window Z accumulation: zs += m_new - hist[u]; hist[u] = m_new.
  // Ring index u is static (loop unrolled by 7) -> stays in registers/AGPRs.
  float zs0[2]={0,0}, zs1[2]={0,0}, zs2[2]={0,0}, zs3[2]={0,0}, zs4[2]={0,0};
  float h0[2][7], h1[2][7], h2[2][7], h3[2][7], h4[2][7];
#pragma unroll
  for (int j = 0; j < 7; ++j) {
    h0[0][j]=0.f; h1[0][j]=0.f; h2[0][j]=0.f; h3[0][j]=0.f; h4[0][j]=0.f;
    h0[1][j]=0.f; h1[1][j]=0.f; h2[1][j]=0.f; h3[1][j]=0.f; h4[1][j]=0.f;
  }
  float p_snv = 0.f, p_sn = 0.f, p_sv = 0.f, p_cnt = 0.f, p_vmin = 3.4e38f;

  loadA(0);
  storeA();
  __syncthreads();

#pragma unroll 1
  for (int sb = 0; sb < NSL; sb += 7) {     // NSL = 28 = 4*7 for EVERY block
#pragma unroll
    for (int u = 0; u < 7; ++u) {
      const int s = sb + u;
      if (s + 1 < NSL) loadA(s + 1);        // global -> regs (stays in flight)
      phaseH();                             // R -> Mh (b64)
      LDS_SYNC();
      {                                     // Phase O: Mh -> sliding-Z + epilogue
#pragma unroll
        for (int rb = 0; rb < 2; ++rb) {
          const int row = ty + (rb << 2);
          float m0 = Mh[0][row][tx], m1 = Mh[1][row][tx], m2 = Mh[2][row][tx],
                m3 = Mh[3][row][tx], m4 = Mh[4][row][tx];
          zs0[rb] += m0 - h0[rb][u]; h0[rb][u] = m0;
          zs1[rb] += m1 - h1[rb][u]; h1[rb][u] = m1;
          zs2[rb] += m2 - h2[rb][u]; h2[rb][u] = m2;
          zs3[rb] += m3 - h3[rb][u]; h3[rb][u] = m3;
          zs4[rb] += m4 - h4[rb][u]; h4[rb][u] = m4;
          if (s >= 6 && (rb ? act1 : act0)) {
            float num = zs4[rb] - zs0[rb] * zs1[rb] * inv_nw;
            float d0  = zs2[rb] - zs0[rb] * zs0[rb] * inv_nw;
            float d1  = zs3[rb] - zs1[rb] * zs1[rb] * inv_nw;
            float den = d0 * d1;
            if (den > 1e-5f) {
              float ncc = num * __frsqrt_rn(den);
              if (ncc >= LO && ncc <= HI) {
                float v = 0.5f * (d0 + d1);
                p_snv += ncc * v; p_sn += ncc; p_sv += v; p_cnt += 1.f;
                p_vmin = fminf(p_vmin, v);
              }
            }
          }
        }
      }
      if (s + 1 < NSL) storeA();            // vmcnt wait lands HERE
      LDS_SYNC();
    }
  }

  // Wave-level reduction (6 shfl each), then 4 partials through LDS.
  float r0 = wave_sum(p_snv);
  float r1 = wave_sum(p_sn);
  float r2 = wave_sum(p_sv);
  float r3 = wave_sum(p_cnt);
  float r4 = wave_min(p_vmin);
  if (tx == 0) {
    red[ty][0]=r0; red[ty][1]=r1; red[ty][2]=r2; red[ty][3]=r3; red[ty][4]=r4;
  }
  __syncthreads();
  if (tid == 0) {
    float s0 = (red[0][0]+red[1][0]) + (red[2][0]+red[3][0]);
    float s1 = (red[0][1]+red[1][1]) + (red[2][1]+red[3][1]);
    float s2 = (red[0][2]+red[1][2]) + (red[2][2]+red[3][2]);
    float s3 = (red[0][3]+red[1][3]) + (red[2][3]+red[3][3]);
    float s4 = fminf(fminf(red[0][4],red[1][4]), fminf(red[2][4],red[3][4]));
    const int bid = blockIdx.x + NWO * (blockIdx.y + NHO * blockIdx.z);
    float* pp = part + (size_t)bid * 8;
    pp[0] = s0; pp[1] = s1; pp[2] = s2; pp[3] = s3; pp[4] = s4;
  }
}

// Reduce NB per-block partials; loss = 1 - (S_nv - vmin*S_n)/(S_v - vmin*cnt)
// (the min-max weight scale HIGH/(vmax-vmin+1e-12) cancels in w/sum(w)).
__global__ __launch_bounds__(256) void fin(const float* __restrict__ part,
                                           float* __restrict__ out) {
  __shared__ float sm[256];
  const int tid = threadIdx.x;
  float s0 = 0.f, s1 = 0.f, s2 = 0.f, s3 = 0.f, vm = 3.4e38f;
  for (int b = tid; b < NB; b += 256) {
    const float* pp = part + (size_t)b * 8;
    s0 += pp[0]; s1 += pp[1]; s2 += pp[2]; s3 += pp[3];
    vm = fminf(vm, pp[4]);
  }
  s0 = block_sum(s0, sm);
  s1 = block_sum(s1, sm);
  s2 = block_sum(s2, sm);
  s3 = block_sum(s3, sm);
  vm = block_min(vm, sm);
  if (tid == 0) {
    out[0] = 1.0f - (s0 - vm * s1) / (s2 - vm * s3);
  }
}

extern "C" void kernel_launch(void* const* d_in, const int* in_sizes, int n_in,
                              void* d_out, int out_size, void* d_ws, size_t ws_size,
                              hipStream_t stream) {
  const float* X = (const float*)d_in[0];  // y_pred
  const float* Y = (const float*)d_in[1];  // y_true
  // d_in[2]: ones kernel, constant, unused.

  float* part = (float*)d_ws;  // NB * 8 floats = 31.5 KB

  dim3 g(NWO, NHO, NN * ZCH);
  ncc_fused<<<g, 256, 0, stream>>>(X, Y, part);
  fin<<<1, 256, 0, stream>>>(part, (float*)d_out);
}